// Round 1
// baseline (587.990 us; speedup 1.0000x reference)
//
#include <hip/hip_runtime.h>

// SNN 2-layer forward: s2 = (( (x@W1.T >=1) @ W2.T) >= 1)
// B=4096, IN=3136, FEAT=6272, OUT=500; x and s1 binary {0,1}.
// Exact 3-limb i8-MFMA GEMM (w = d0*2^-7+d1*2^-14+d2*2^-21+r, |r|<=2^-22,
// i32 MFMA accumulation exact, f64 Horner exact) + worst-case-safe sparse
// fp64 correction of all dots with |v_hat-1| <= K*2^-22.
//
// Round-9: R8's fc1 was barrier-drain bound (MfmaUtil 45% vs 110us MFMA
// floor at 256us measured; __syncthreads emits vmcnt(0) each kt, draining
// stage loads that are L2 misses (FETCH 236MB = 4x w1lF -> L3/HBM latency
// ~500-900cy ~= one compute phase)). Fix per T3+T4: triple-buffered LDS
// (3x12KB), 2-deep global_load_lds prefetch, raw s_barrier + counted
// s_waitcnt vmcnt(3/2) (never 0 in the loop); K-loop unrolled x6 so buffer
// offsets are compile-time and A regs alternate by name (no rotation copy
// -> no compiler vmcnt(0)). Plus T1 XCD swizzle (panel's 32 M-blocks on
// one XCD -> one L2 fill per panel) and T5 setprio around MFMA clusters.

namespace {
constexpr int kB = 4096;
constexpr int kIn = 3136;        // 49 chunks of 64
constexpr int kFeat = 6272;      // 98 chunks of 64
constexpr int kFeatWords = 196;  // u32 per s1 row
constexpr int kOut = 500;
constexpr size_t kPlane1 = (size_t)kFeat * kIn;
constexpr size_t kW1F = 3 * kPlane1;                 // 59,006,976 (4802*12288)
constexpr size_t kW2F = (size_t)784 * 12288;         // 9,633,792
constexpr size_t kS1Bytes = (size_t)kB * kFeatWords * 4;  // 3,211,264 (x2)
constexpr size_t kXb2Bytes = (size_t)49 * kB * 8;    // 1,605,632
constexpr unsigned kCap1 = 2u << 20;
constexpr unsigned kCap2 = 1u << 16;
__device__ constexpr double kTau1 = 7.4769e-4;       // > 3136*2^-22
__device__ constexpr double kTau2 = 1.4955e-3;       // > 6272*2^-22
}  // namespace

typedef int v4i __attribute__((ext_vector_type(4)));
typedef int v16i __attribute__((ext_vector_type(16)));

__device__ __forceinline__ void gload_lds16(const void* g, void* l) {
  __builtin_amdgcn_global_load_lds((__attribute__((address_space(1))) void*)(g),
                                   (__attribute__((address_space(3))) void*)(l),
                                   16, 0, 0);
}

// 16 bits -> 16 i8 (byte i = bit i)
__device__ __forceinline__ v4i expand16(unsigned b) {
  unsigned u0 = (((b      ) & 0xFu) * 0x204081u) & 0x01010101u;
  unsigned u1 = (((b >> 4 ) & 0xFu) * 0x204081u) & 0x01010101u;
  unsigned u2 = (((b >> 8 ) & 0xFu) * 0x204081u) & 0x01010101u;
  unsigned u3 = (((b >> 12) & 0xFu) * 0x204081u) & 0x01010101u;
  return (v4i){(int)u0, (int)u1, (int)u2, (int)u3};
}

// exact 3-digit signed base-128 split; |w - sum| <= 2^-22
__device__ __forceinline__ void split3(float w, signed char* d) {
  float c = rintf(w * 128.f);
  d[0] = (signed char)(int)c;
  float r = fmaf(c, -7.8125e-03f, w);
  c = rintf(r * 16384.f);
  d[1] = (signed char)(int)c;
  r = fmaf(c, -6.103515625e-05f, r);
  c = rintf(r * 2097152.f);
  d[2] = (signed char)(int)c;
}

// ---------------------------------------------------------------------------
// W1 -> fragment-major limbs: slot(fb,kt,j,g) = 1KB of 64 feats x 16 k-bytes.
// ---------------------------------------------------------------------------
__global__ __launch_bounds__(256) void conv_w1F(const float* __restrict__ W,
                                                signed char* __restrict__ F) {
  const int bx = blockIdx.x;               // fb*49 + kt, < 4802
  const int fb = bx / 49;
  const int kt = bx % 49;
  const int f = threadIdx.x & 63;
  const int g = threadIdx.x >> 6;
  const float* src = W + (size_t)(fb * 64 + f) * kIn + kt * 64 + g * 16;
  union { signed char c[16]; int4 v; } o[3];
#pragma unroll
  for (int q = 0; q < 4; ++q) {
    const float4 w = *(const float4*)(src + q * 4);
    signed char d[4][3];
    split3(w.x, d[0]); split3(w.y, d[1]); split3(w.z, d[2]); split3(w.w, d[3]);
#pragma unroll
    for (int e = 0; e < 4; ++e)
#pragma unroll
      for (int j = 0; j < 3; ++j) o[j].c[q * 4 + e] = d[e][j];
  }
#pragma unroll
  for (int j = 0; j < 3; ++j)
    *(int4*)(F + ((size_t)bx * 3 + j) * 4096 + g * 1024 + f * 16) = o[j].v;
}

// W2 (padded to 512 rows) -> fragment-major limbs, slots (fb<8, kt<98, j, g)
__global__ __launch_bounds__(256) void conv_w2F(const float* __restrict__ W,
                                                signed char* __restrict__ F) {
  const int bx = blockIdx.x;               // fb*98 + kt, < 784
  const int fb = bx / 98;
  const int kt = bx % 98;
  const int f = threadIdx.x & 63;
  const int g = threadIdx.x >> 6;
  const int feat = fb * 64 + f;
  union { signed char c[16]; int4 v; } o[3];
#pragma unroll
  for (int q = 0; q < 4; ++q) {
    float4 w = {0.f, 0.f, 0.f, 0.f};
    if (feat < kOut)
      w = *(const float4*)(W + (size_t)feat * kFeat + kt * 64 + g * 16 + q * 4);
    signed char d[4][3];
    split3(w.x, d[0]); split3(w.y, d[1]); split3(w.z, d[2]); split3(w.w, d[3]);
#pragma unroll
    for (int e = 0; e < 4; ++e)
#pragma unroll
      for (int j = 0; j < 3; ++j) o[j].c[q * 4 + e] = d[e][j];
  }
#pragma unroll
  for (int j = 0; j < 3; ++j)
    *(int4*)(F + ((size_t)bx * 3 + j) * 4096 + g * 1024 + f * 16) = o[j].v;
}

// x -> transposed packed bits: xb2[kt*4096 + b]
__global__ __launch_bounds__(256) void pack_x2(const float* __restrict__ X,
                                               uint2* __restrict__ xb2) {
  const int wid = (blockIdx.x * 256 + threadIdx.x) >> 6;  // < 200,704
  const int lane = threadIdx.x & 63;
  const int b = wid / 49;
  const int g = wid % 49;
  const float v = X[(size_t)b * kIn + g * 64 + lane];
  const unsigned long long bal = __ballot(v != 0.f);
  if (lane == 0) xb2[(size_t)g * kB + b] = make_uint2((unsigned)bal, (unsigned)(bal >> 32));
}

// ---------------------------------------------------------------------------
// FC1 v7: tile M=128,N=64,BK=64; 512 thr = 8 waves (4 waveM x 2 waveN),
// wave tile 32x32, acc[3] (48 AGPR). Triple-buffered LDS (3x12KB), 2-deep
// global_load_lds prefetch, raw s_barrier + counted vmcnt (3/2; never 0 in
// the main loop). K-loop unrolled x6 (lcm of buf period 3, A dbuf period 2)
// -> all buffer offsets compile-time, no A rotation copies. XCD swizzle:
// the 32 M-blocks of one N-panel land on one XCD (one L2 fill per panel).
// Grid (32, 98).
// ---------------------------------------------------------------------------
__global__ __launch_bounds__(512, 4) void fc1_v7(
    const uint2* __restrict__ xb2, const signed char* __restrict__ w1lF,
    unsigned* __restrict__ s1b, unsigned* __restrict__ s1T,
    unsigned* __restrict__ cnt, unsigned* __restrict__ list) {
  __shared__ __align__(16) signed char lds[36864];  // 3 x 12 KB
  const int tid = threadIdx.x;
  const int lane = tid & 63;
  const int ln31 = lane & 31;
  const int half = lane >> 5;
  const int wv = tid >> 6;       // 0..7
  const int waveM = wv >> 1;     // 0..3
  const int waveN = wv & 1;      // 0..1

  // XCD-aware swizzle: linear id -> contiguous 392-block chunk per XCD so
  // one panel's 32 M-blocks co-reside on one XCD. 3136 = 8*392 (bijective).
  const int lin = blockIdx.x + 32 * blockIdx.y;     // 0..3135
  const int sw = (lin & 7) * 392 + (lin >> 3);
  const int bx = sw >> 5;        // N-block (64 feats), 0..97
  const int bM = (sw & 31) * 128;

  // B staging: 12 slots/tile; wave wv stages slot wv, and wv+8 if wv<4
  const signed char* const gbase = w1lF + (size_t)bx * 49 * 12288;
  const bool has1 = (wv < 4);
  const unsigned sG0 = wv * 1024u + lane * 16u;
  const unsigned sL0 = wv * 1024u;
  const unsigned sG1 = (wv + 8) * 1024u + lane * 16u;
  const unsigned sL1 = (wv + 8) * 1024u;

  const uint2* const aptr = xb2 + bM + waveM * 32 + ln31;
  const unsigned bfeat = (waveN * 32 + ln31) * 16u;

  v16i acc[3] = {};
  uint2 aC, aN;

#define FC1_TILE(CBC, AA)                                                     \
  {                                                                           \
    _Pragma("unroll")                                                         \
    for (int kk = 0; kk < 2; ++kk) {                                          \
      const unsigned gsel = (kk * 2 + half) * 1024u;                          \
      const v4i b0 = *(const v4i*)(lds + (CBC) + 0 * 4096 + gsel + bfeat);    \
      const v4i b1 = *(const v4i*)(lds + (CBC) + 1 * 4096 + gsel + bfeat);    \
      const v4i b2 = *(const v4i*)(lds + (CBC) + 2 * 4096 + gsel + bfeat);    \
      const unsigned word = kk ? (AA).y : (AA).x;                             \
      const v4i a = expand16((word >> (half * 16)) & 0xFFFFu);                \
      __builtin_amdgcn_s_setprio(1);                                          \
      acc[0] = __builtin_amdgcn_mfma_i32_32x32x32_i8(a, b0, acc[0], 0, 0, 0); \
      acc[1] = __builtin_amdgcn_mfma_i32_32x32x32_i8(a, b1, acc[1], 0, 0, 0); \
      acc[2] = __builtin_amdgcn_mfma_i32_32x32x32_i8(a, b2, acc[2], 0, 0, 0); \
      __builtin_amdgcn_s_setprio(0);                                          \
    }                                                                         \
  }

  // One pipelined K-step: load A(kt+1), stage S(kt+2) into buffer SBC,
  // compute tile kt from buffer CBC, then wait so that S(kt+1) is certainly
  // complete (everything except this step's own 3 (or 2) VMEM ops) and
  // barrier. The counted vmcnt keeps the 2-deep stage prefetch in flight.
#define FC1_STEP(CBC, SBC, AUSE, ALOAD)                                       \
  {                                                                           \
    ALOAD = *apre;                                                            \
    apre += kB;                                                               \
    gload_lds16(gstage + sG0, lds + (SBC) + sL0);                             \
    if (has1) gload_lds16(gstage + sG1, lds + (SBC) + sL1);                   \
    gstage += 12288;                                                          \
    FC1_TILE(CBC, AUSE);                                                      \
    if (has1) asm volatile("s_waitcnt vmcnt(3)" ::: "memory");                \
    else      asm volatile("s_waitcnt vmcnt(2)" ::: "memory");                \
    __builtin_amdgcn_s_barrier();                                             \
    asm volatile("" ::: "memory");                                            \
  }

  // ---- prologue: A(0); stage S(0)->buf0, S(1)->buf1; certify S(0) ----
  aC = aptr[0];
  asm volatile("" ::: "memory");  // pin A(0) before the stage issues
  gload_lds16(gbase + sG0, lds + sL0);
  if (has1) gload_lds16(gbase + sG1, lds + sL1);
  gload_lds16(gbase + 12288 + sG0, lds + 12288 + sL0);
  if (has1) gload_lds16(gbase + 12288 + sG1, lds + 12288 + sL1);
  if (has1) asm volatile("s_waitcnt vmcnt(2)" ::: "memory");
  else      asm volatile("s_waitcnt vmcnt(1)" ::: "memory");
  __builtin_amdgcn_s_barrier();
  asm volatile("" ::: "memory");

  const uint2* apre = aptr + (size_t)kB;            // -> A(1)
  const signed char* gstage = gbase + 2 * 12288;    // -> S(2)

  // ---- main loop: kt = 0..41 (7 x 6 steps; cb period 3, A period 2) ----
  for (int t = 0; t < 7; ++t) {
    FC1_STEP(0,     24576, aC, aN);   // kt%6==0
    FC1_STEP(12288, 0,     aN, aC);   // kt%6==1
    FC1_STEP(24576, 12288, aC, aN);   // kt%6==2
    FC1_STEP(0,     24576, aN, aC);   // kt%6==3
    FC1_STEP(12288, 0,     aC, aN);   // kt%6==4
    FC1_STEP(24576, 12288, aN, aC);   // kt%6==5
  }
  // ---- tail: kt = 42..46 still stage (S(44)..S(48)) ----
  FC1_STEP(0,     24576, aC, aN);   // kt=42
  FC1_STEP(12288, 0,     aN, aC);   // kt=43
  FC1_STEP(24576, 12288, aC, aN);   // kt=44
  FC1_STEP(0,     24576, aN, aC);   // kt=45
  FC1_STEP(12288, 0,     aC, aN);   // kt=46 stages S(48)->buf0
  // ---- kt=47: compute buf2 with A(47)=aN; load A(48); drain; kt=48 ----
  aC = *apre;                        // A(48)
  FC1_TILE(24576, aN);               // kt=47
  asm volatile("s_waitcnt vmcnt(0)" ::: "memory");
  __builtin_amdgcn_s_barrier();
  asm volatile("" ::: "memory");
  FC1_TILE(0, aC);                   // kt=48

#undef FC1_STEP

  const double s7 = 0.0078125;
  const int word = bx * 2 + waveN;
  const int fcol = word * 32 + ln31;
#pragma unroll
  for (int t = 0; t < 16; ++t) {
    double v = (double)acc[2][t];
    v = v * s7 + (double)acc[1][t];
    v = v * s7 + (double)acc[0][t];
    v = v * s7;
    const unsigned long long bal = __ballot(v >= 1.0);
    const int mrow = bM + waveM * 32 + (t & 3) + 8 * (t >> 2);
    if (lane == 0) {
      s1b[(size_t)mrow * kFeatWords + word] = (unsigned)bal;
      s1T[(size_t)word * kB + mrow] = (unsigned)bal;
    }
    if (lane == 32) {
      s1b[(size_t)(mrow + 4) * kFeatWords + word] = (unsigned)(bal >> 32);
      s1T[(size_t)word * kB + mrow + 4] = (unsigned)(bal >> 32);
    }
    if (fabs(v - 1.0) <= kTau1) {
      const unsigned idx = atomicAdd(cnt, 1u);
      if (idx < kCap1) list[idx] = ((unsigned)(mrow + 4 * half) << 13) | (unsigned)fcol;
    }
  }
#undef FC1_TILE
}

// exact fp64 recompute of flagged FC1 dots; fixes s1b AND s1T
__global__ __launch_bounds__(256) void fc1_correct(
    const float* __restrict__ x, const float* __restrict__ W1,
    const unsigned* __restrict__ cnt, const unsigned* __restrict__ list,
    unsigned* __restrict__ s1b, unsigned* __restrict__ s1T) {
  const unsigned n = min(cnt[0], kCap1);
  const int lane = threadIdx.x & 63;
  const int wid = (blockIdx.x * 256 + threadIdx.x) >> 6;
  const int nw = (gridDim.x * 256) >> 6;
  for (unsigned i = wid; i < n; i += nw) {
    const unsigned u = list[i];
    const int b = (int)(u >> 13);
    const int f = (int)(u & 8191u);
    double s = 0.0;
    for (int k = lane; k < kIn; k += 64)
      s = fma((double)x[(size_t)b * kIn + k], (double)W1[(size_t)f * kIn + k], s);
#pragma unroll
    for (int off = 32; off > 0; off >>= 1) s += __shfl_down(s, off);
    if (lane == 0) {
      const unsigned mask = 1u << (f & 31);
      unsigned* p1 = s1b + (size_t)b * kFeatWords + (f >> 5);
      unsigned* p2 = s1T + (size_t)(f >> 5) * kB + b;
      if (s >= 1.0) { atomicOr(p1, mask); atomicOr(p2, mask); }
      else          { atomicAnd(p1, ~mask); atomicAnd(p2, ~mask); }
    }
  }
}

// ---------------------------------------------------------------------------
// FC2 v7: barrier-free register-dbuf, 2-wave blocks (tile 32 rows x 64 outs),
// grid (128, 8) = 1024 blocks -> 8 blocks/CU for latency interleave. A bits
// from s1T, B frags dwordx4 from L2. XCD swizzle: each XCD owns one N-panel.
// ---------------------------------------------------------------------------
__global__ __launch_bounds__(128, 4) void fc2_v7(
    const unsigned* __restrict__ s1T, const signed char* __restrict__ w2lF,
    float* __restrict__ out, unsigned* __restrict__ cnt,
    unsigned* __restrict__ list) {
  const int tid = threadIdx.x;
  const int lane = tid & 63;
  const int ln31 = lane & 31;
  const int half = lane >> 5;
  const int wvN = tid >> 6;    // 0..1 (waveN)

  const int lin = blockIdx.x + 128 * blockIdx.y;    // 0..1023
  const int sw = ((lin & 7) << 7) + (lin >> 3);     // 1024 = 8*128
  const int bx = sw >> 7;      // N-block (64 outs), 0..7
  const int bM = (sw & 127) * 32;

  const unsigned* const aptr = s1T + bM + ln31;
  const int fl = wvN * 32 + ln31;
  const signed char* const bbase =
      w2lF + (size_t)(bx * 98) * 12288 + half * 1024u + fl * 16u;

  v16i acc[3] = {};
  v4i b0[6], b1[6];
  uint2 a0, a1;

#define LOAD_TILE(nk, bf, ab)                                   \
  {                                                             \
    const signed char* bp = bbase + (size_t)(nk) * 12288;       \
    bf[0] = *(const v4i*)(bp);                                  \
    bf[1] = *(const v4i*)(bp + 2048);                           \
    bf[2] = *(const v4i*)(bp + 4096);                           \
    bf[3] = *(const v4i*)(bp + 6144);                           \
    bf[4] = *(const v4i*)(bp + 8192);                           \
    bf[5] = *(const v4i*)(bp + 10240);                          \
    (ab).x = aptr[(size_t)((nk) * 2) * kB];                     \
    (ab).y = aptr[(size_t)((nk) * 2 + 1) * kB];                 \
  }
#define COMPUTE_TILE(bf, ab)                                                    \
  {                                                                             \
    _Pragma("unroll")                                                           \
    for (int kk = 0; kk < 2; ++kk) {                                            \
      const unsigned word = kk ? (ab).y : (ab).x;                               \
      const v4i a = expand16((word >> (half * 16)) & 0xFFFFu);                  \
      acc[0] = __builtin_amdgcn_mfma_i32_32x32x32_i8(a, bf[kk], acc[0], 0,0,0); \
      acc[1] = __builtin_amdgcn_mfma_i32_32x32x32_i8(a, bf[2+kk], acc[1],0,0,0);\
      acc[2] = __builtin_amdgcn_mfma_i32_32x32x32_i8(a, bf[4+kk], acc[2],0,0,0);\
    }                                                                           \
  }

  LOAD_TILE(0, b0, a0);
  for (int kt = 0; kt + 2 <= 98; kt += 2) {
    LOAD_TILE(kt + 1, b1, a1);
    COMPUTE_TILE(b0, a0);
    const int nk2 = (kt + 2 < 98) ? kt + 2 : 97;  // last reload harmless
    LOAD_TILE(nk2, b0, a0);
    COMPUTE_TILE(b1, a1);
  }

  const double s7 = 0.0078125;
  const int o = bx * 64 + wvN * 32 + ln31;
#pragma unroll
  for (int t = 0; t < 16; ++t) {
    double v = (double)acc[2][t];
    v = v * s7 + (double)acc[1][t];
    v = v * s7 + (double)acc[0][t];
    v = v * s7;
    const int b = bM + (t & 3) + 8 * (t >> 2) + 4 * half;
    if (o < kOut) {
      out[(size_t)b * kOut + o] = (v >= 1.0) ? 1.0f : 0.0f;
      if (fabs(v - 1.0) <= kTau2) {
        const unsigned idx = atomicAdd(cnt, 1u);
        if (idx < kCap2) list[idx] = ((unsigned)b << 13) | (unsigned)o;
      }
    }
  }
#undef LOAD_TILE
#undef COMPUTE_TILE
}

// exact fp64 recompute of flagged FC2 dots (reads row-major s1b)
__global__ __launch_bounds__(256) void fc2_correct(
    const unsigned* __restrict__ s1b, const float* __restrict__ W2,
    const unsigned* __restrict__ cnt, const unsigned* __restrict__ list,
    float* __restrict__ out) {
  const unsigned n = min(cnt[0], kCap2);
  const int lane = threadIdx.x & 63;
  const int wid = (blockIdx.x * 256 + threadIdx.x) >> 6;
  const int nw = (gridDim.x * 256) >> 6;
  for (unsigned i = wid; i < n; i += nw) {
    const unsigned u = list[i];
    const int b = (int)(u >> 13);
    const int o = (int)(u & 8191u);
    double s = 0.0;
    for (int k = lane; k < kFeat; k += 64) {
      const unsigned w = s1b[(size_t)b * kFeatWords + (k >> 5)];
      if ((w >> (k & 31)) & 1u) s += (double)W2[(size_t)o * kFeat + k];
    }
#pragma unroll
    for (int off = 32; off > 0; off >>= 1) s += __shfl_down(s, off);
    if (lane == 0) out[(size_t)b * kOut + o] = (s >= 1.0) ? 1.0f : 0.0f;
  }
}

// ---------------------------------------------------------------------------
// fp64 fallback (round-1 validated) — only if ws too small.
// ---------------------------------------------------------------------------
__global__ __launch_bounds__(256) void snn_fc1(const float* __restrict__ x,
                                               const float* __restrict__ W1,
                                               unsigned int* __restrict__ s1bits) {
  __shared__ double Xd[32][66];
  __shared__ double Wd[32][66];
  __shared__ unsigned int spikes[64][2];
  const int tid = threadIdx.x;
  const int tx = tid & 15;
  const int ty = tid >> 4;
  const int b0 = blockIdx.y * 64;
  const int f0 = blockIdx.x * 64;
  if (tid < 128) spikes[tid >> 1][tid & 1] = 0u;
  double acc[4][4];
#pragma unroll
  for (int j = 0; j < 4; ++j)
#pragma unroll
    for (int i = 0; i < 4; ++i) acc[j][i] = 0.0;
  const int rl = tid >> 2;
  const int kq = (tid & 3) * 8;
  const float* xrow = x + (size_t)(b0 + rl) * kIn + kq;
  const float* wrow = W1 + (size_t)(f0 + rl) * kIn + kq;
  for (int kc = 0; kc < kIn; kc += 32) {
    const float4 xv0 = *(const float4*)(xrow + kc);
    const float4 xv1 = *(const float4*)(xrow + kc + 4);
    const float4 wv0 = *(const float4*)(wrow + kc);
    const float4 wv1 = *(const float4*)(wrow + kc + 4);
    __syncthreads();
    Xd[kq + 0][rl] = (double)xv0.x; Xd[kq + 1][rl] = (double)xv0.y;
    Xd[kq + 2][rl] = (double)xv0.z; Xd[kq + 3][rl] = (double)xv0.w;
    Xd[kq + 4][rl] = (double)xv1.x; Xd[kq + 5][rl] = (double)xv1.y;
    Xd[kq + 6][rl] = (double)xv1.z; Xd[kq + 7][rl] = (double)xv1.w;
    Wd[kq + 0][rl] = (double)wv0.x; Wd[kq + 1][rl] = (double)wv0.y;
    Wd[kq + 2][rl] = (double)wv0.z; Wd[kq + 3][rl] = (double)wv0.w;
    Wd[kq + 4][rl] = (double)wv1.x; Wd[kq + 5][rl] = (double)wv1.y;
    Wd[kq + 6][rl] = (double)wv1.z; Wd[kq + 7][rl] = (double)wv1.w;
    __syncthreads();
#pragma unroll
    for (int k = 0; k < 32; ++k) {
      const double2 xa = *(const double2*)&Xd[k][ty * 4];
      const double2 xb = *(const double2*)&Xd[k][ty * 4 + 2];
      const double2 wa = *(const double2*)&Wd[k][tx * 4];
      const double2 wb = *(const double2*)&Wd[k][tx * 4 + 2];
      const double xv[4] = {xa.x, xa.y, xb.x, xb.y};
      const double wv[4] = {wa.x, wa.y, wb.x, wb.y};
#pragma unroll
      for (int j = 0; j < 4; ++j)
#pragma unroll
        for (int i = 0; i < 4; ++i) acc[j][i] += xv[j] * wv[i];
    }
  }
  __syncthreads();
#pragma unroll
  for (int j = 0; j < 4; ++j) {
    unsigned int nib = 0u;
#pragma unroll
    for (int i = 0; i < 4; ++i) nib |= (acc[j][i] >= 1.0 ? 1u : 0u) << i;
    atomicOr(&spikes[ty * 4 + j][tx >> 3], nib << ((tx * 4) & 31));
  }
  __syncthreads();
  if (tid < 128) {
    const int r = tid >> 1;
    const int w = tid & 1;
    s1bits[(size_t)(b0 + r) * kFeatWords + (f0 >> 5) + w] = spikes[r][w];
  }
}

__global__ __launch_bounds__(256) void snn_fc2(const unsigned int* __restrict__ s1bits,
                                               const float* __restrict__ W2,
                                               float* __restrict__ out) {
  __shared__ double Wd[32][66];
  __shared__ unsigned int Sb[64];
  const int tid = threadIdx.x;
  const int tx = tid & 15;
  const int ty = tid >> 4;
  const int b0 = blockIdx.y * 64;
  const int o0 = blockIdx.x * 64;
  double acc[4][4];
#pragma unroll
  for (int j = 0; j < 4; ++j)
#pragma unroll
    for (int i = 0; i < 4; ++i) acc[j][i] = 0.0;
  const int rl = tid >> 2;
  const int kq = (tid & 3) * 8;
  int orow = o0 + rl;
  if (orow >= kOut) orow = kOut - 1;
  const float* wrow = W2 + (size_t)orow * kFeat + kq;
  for (int kc = 0; kc < kFeat; kc += 32) {
    const float4 wv0 = *(const float4*)(wrow + kc);
    const float4 wv1 = *(const float4*)(wrow + kc + 4);
    unsigned int sword = 0u;
    if (tid < 64) sword = s1bits[(size_t)(b0 + tid) * kFeatWords + (kc >> 5)];
    __syncthreads();
    Wd[kq + 0][rl] = (double)wv0.x; Wd[kq + 1][rl] = (double)wv0.y;
    Wd[kq + 2][rl] = (double)wv0.z; Wd[kq + 3][rl] = (double)wv0.w;
    Wd[kq + 4][rl] = (double)wv1.x; Wd[kq + 5][rl] = (double)wv1.y;
    Wd[kq + 6][rl] = (double)wv1.z; Wd[kq + 7][rl] = (double)wv1.w;
    if (tid < 64) Sb[tid] = sword;
    __syncthreads();
    const unsigned int rw0 = Sb[ty * 4 + 0];
    const unsigned int rw1 = Sb[ty * 4 + 1];
    const unsigned int rw2 = Sb[ty * 4 + 2];
    const unsigned int rw3 = Sb[ty * 4 + 3];
#pragma unroll
    for (int k = 0; k < 32; ++k) {
      const double2 wa = *(const double2*)&Wd[k][tx * 4];
      const double2 wb = *(const double2*)&Wd[k][tx * 4 + 2];
      const double wv[4] = {wa.x, wa.y, wb.x, wb.y};
      const double sv[4] = {(double)((rw0 >> k) & 1u), (double)((rw1 >> k) & 1u),
                            (double)((rw2 >> k) & 1u), (double)((rw3 >> k) & 1u)};
#pragma unroll
      for (int j = 0; j < 4; ++j)
#pragma unroll
        for (int i = 0; i < 4; ++i) acc[j][i] += sv[j] * wv[i];
    }
  }
#pragma unroll
  for (int j = 0; j < 4; ++j) {
    const int b = b0 + ty * 4 + j;
#pragma unroll
    for (int i = 0; i < 4; ++i) {
      const int o = o0 + tx * 4 + i;
      if (o < kOut) out[(size_t)b * kOut + o] = (acc[j][i] >= 1.0) ? 1.0f : 0.0f;
    }
  }
}

extern "C" void kernel_launch(void* const* d_in, const int* in_sizes, int n_in,
                              void* d_out, int out_size, void* d_ws, size_t ws_size,
                              hipStream_t stream) {
  const float* x = (const float*)d_in[0];
  const float* W1 = (const float*)d_in[1];
  const float* W2 = (const float*)d_in[2];
  float* out = (float*)d_out;

  char* p = (char*)d_ws;
  signed char* w1lF = (signed char*)p;   p += kW1F;
  signed char* w2lF = (signed char*)p;   p += kW2F;
  unsigned* s1b = (unsigned*)p;          p += kS1Bytes;
  unsigned* s1T = (unsigned*)p;          p += kS1Bytes;
  uint2* xb2 = (uint2*)p;                p += kXb2Bytes;
  unsigned* list1 = (unsigned*)p;        p += (size_t)kCap1 * 4;
  unsigned* list2 = (unsigned*)p;        p += (size_t)kCap2 * 4;
  unsigned* ctrs = (unsigned*)p;         p += 256;
  const size_t need = (size_t)(p - (char*)d_ws);  // ~85 MB

  if (ws_size >= need) {
    hipMemsetAsync(ctrs, 0, 32, stream);  // ctrs[0]=fc1 cnt, ctrs[4]=fc2 cnt
    conv_w1F<<<4802, 256, 0, stream>>>(W1, w1lF);
    conv_w2F<<<784, 256, 0, stream>>>(W2, w2lF);
    pack_x2<<<50176, 256, 0, stream>>>(x, xb2);
    fc1_v7<<<dim3(32, 98), 512, 0, stream>>>(xb2, w1lF, s1b, s1T, ctrs, list1);
    fc1_correct<<<1024, 256, 0, stream>>>(x, W1, ctrs, list1, s1b, s1T);
    fc2_v7<<<dim3(128, 8), 128, 0, stream>>>(s1T, w2lF, out, ctrs + 4, list2);
    fc2_correct<<<64, 256, 0, stream>>>(s1b, W2, ctrs + 4, list2, out);
  } else {
    unsigned* s1 = (unsigned*)d_ws;
    snn_fc1<<<dim3(98, 64), 256, 0, stream>>>(x, W1, s1);
    snn_fc2<<<dim3(8, 64), 256, 0, stream>>>(s1, W2, out);
  }
}

// Round 3
// 587.024 us; speedup vs baseline: 1.0016x; 1.0016x over previous
//
#include <hip/hip_runtime.h>

// SNN 2-layer forward: s2 = (( (x@W1.T >=1) @ W2.T) >= 1)
// B=4096, IN=3136, FEAT=6272, OUT=500; x and s1 binary {0,1}.
// Exact 3-limb i8-MFMA GEMM (w = d0*2^-7+d1*2^-14+d2*2^-21+r, |r|<=2^-22,
// i32 MFMA accumulation exact, f64 Horner exact) + worst-case-safe sparse
// fp64 correction of all dots with |v_hat-1| <= K*2^-22.
//
// Round-11 == Round-10 resubmit (container infra failure, no verdict).
// R9 killed HBM over-fetch (XCD swizzle: FETCH 236->39MB) but fc1 stayed
// at MfmaUtil 40% -> the stall was never the vmcnt(0) drain; it is the
// post-barrier front latency (6 ds_read_b128 + expand on an empty MFMA
// pipe, x49 phases, barrier-aligned so never hidden). Matches m218/m196:
// counted vmcnt is null without the fine interleave. Fix: register-
// prefetch B-frags one phase ahead (kk0 set prefetched at end of prev
// phase; kk1 set read in-phase under the kk0 MFMAs), 4 LDS buffers (48KB)
// with stages 3 phases ahead so certification needs no drain. Post-barrier
// chain = expand16 -> MFMA. Setprio removed (T5 null at 2-phase).
// +24 VGPR (~120 total incl AGPR) keeps 4 waves/SIMD.

namespace {
constexpr int kB = 4096;
constexpr int kIn = 3136;        // 49 chunks of 64
constexpr int kFeat = 6272;      // 98 chunks of 64
constexpr int kFeatWords = 196;  // u32 per s1 row
constexpr int kOut = 500;
constexpr size_t kPlane1 = (size_t)kFeat * kIn;
constexpr size_t kW1F = 3 * kPlane1;                 // 59,006,976 (4802*12288)
constexpr size_t kW2F = (size_t)784 * 12288;         // 9,633,792
constexpr size_t kS1Bytes = (size_t)kB * kFeatWords * 4;  // 3,211,264 (x2)
constexpr size_t kXb2Bytes = (size_t)49 * kB * 8;    // 1,605,632
constexpr unsigned kCap1 = 2u << 20;
constexpr unsigned kCap2 = 1u << 16;
__device__ constexpr double kTau1 = 7.4769e-4;       // > 3136*2^-22
__device__ constexpr double kTau2 = 1.4955e-3;       // > 6272*2^-22
}  // namespace

typedef int v4i __attribute__((ext_vector_type(4)));
typedef int v16i __attribute__((ext_vector_type(16)));

__device__ __forceinline__ void gload_lds16(const void* g, void* l) {
  __builtin_amdgcn_global_load_lds((__attribute__((address_space(1))) void*)(g),
                                   (__attribute__((address_space(3))) void*)(l),
                                   16, 0, 0);
}

// 16 bits -> 16 i8 (byte i = bit i)
__device__ __forceinline__ v4i expand16(unsigned b) {
  unsigned u0 = (((b      ) & 0xFu) * 0x204081u) & 0x01010101u;
  unsigned u1 = (((b >> 4 ) & 0xFu) * 0x204081u) & 0x01010101u;
  unsigned u2 = (((b >> 8 ) & 0xFu) * 0x204081u) & 0x01010101u;
  unsigned u3 = (((b >> 12) & 0xFu) * 0x204081u) & 0x01010101u;
  return (v4i){(int)u0, (int)u1, (int)u2, (int)u3};
}

// exact 3-digit signed base-128 split; |w - sum| <= 2^-22
__device__ __forceinline__ void split3(float w, signed char* d) {
  float c = rintf(w * 128.f);
  d[0] = (signed char)(int)c;
  float r = fmaf(c, -7.8125e-03f, w);
  c = rintf(r * 16384.f);
  d[1] = (signed char)(int)c;
  r = fmaf(c, -6.103515625e-05f, r);
  c = rintf(r * 2097152.f);
  d[2] = (signed char)(int)c;
}

// ---------------------------------------------------------------------------
// W1 -> fragment-major limbs: slot(fb,kt,j,g) = 1KB of 64 feats x 16 k-bytes.
// ---------------------------------------------------------------------------
__global__ __launch_bounds__(256) void conv_w1F(const float* __restrict__ W,
                                                signed char* __restrict__ F) {
  const int bx = blockIdx.x;               // fb*49 + kt, < 4802
  const int fb = bx / 49;
  const int kt = bx % 49;
  const int f = threadIdx.x & 63;
  const int g = threadIdx.x >> 6;
  const float* src = W + (size_t)(fb * 64 + f) * kIn + kt * 64 + g * 16;
  union { signed char c[16]; int4 v; } o[3];
#pragma unroll
  for (int q = 0; q < 4; ++q) {
    const float4 w = *(const float4*)(src + q * 4);
    signed char d[4][3];
    split3(w.x, d[0]); split3(w.y, d[1]); split3(w.z, d[2]); split3(w.w, d[3]);
#pragma unroll
    for (int e = 0; e < 4; ++e)
#pragma unroll
      for (int j = 0; j < 3; ++j) o[j].c[q * 4 + e] = d[e][j];
  }
#pragma unroll
  for (int j = 0; j < 3; ++j)
    *(int4*)(F + ((size_t)bx * 3 + j) * 4096 + g * 1024 + f * 16) = o[j].v;
}

// W2 (padded to 512 rows) -> fragment-major limbs, slots (fb<8, kt<98, j, g)
__global__ __launch_bounds__(256) void conv_w2F(const float* __restrict__ W,
                                                signed char* __restrict__ F) {
  const int bx = blockIdx.x;               // fb*98 + kt, < 784
  const int fb = bx / 98;
  const int kt = bx % 98;
  const int f = threadIdx.x & 63;
  const int g = threadIdx.x >> 6;
  const int feat = fb * 64 + f;
  union { signed char c[16]; int4 v; } o[3];
#pragma unroll
  for (int q = 0; q < 4; ++q) {
    float4 w = {0.f, 0.f, 0.f, 0.f};
    if (feat < kOut)
      w = *(const float4*)(W + (size_t)feat * kFeat + kt * 64 + g * 16 + q * 4);
    signed char d[4][3];
    split3(w.x, d[0]); split3(w.y, d[1]); split3(w.z, d[2]); split3(w.w, d[3]);
#pragma unroll
    for (int e = 0; e < 4; ++e)
#pragma unroll
      for (int j = 0; j < 3; ++j) o[j].c[q * 4 + e] = d[e][j];
  }
#pragma unroll
  for (int j = 0; j < 3; ++j)
    *(int4*)(F + ((size_t)bx * 3 + j) * 4096 + g * 1024 + f * 16) = o[j].v;
}

// x -> transposed packed bits: xb2[kt*4096 + b]
__global__ __launch_bounds__(256) void pack_x2(const float* __restrict__ X,
                                               uint2* __restrict__ xb2) {
  const int wid = (blockIdx.x * 256 + threadIdx.x) >> 6;  // < 200,704
  const int lane = threadIdx.x & 63;
  const int b = wid / 49;
  const int g = wid % 49;
  const float v = X[(size_t)b * kIn + g * 64 + lane];
  const unsigned long long bal = __ballot(v != 0.f);
  if (lane == 0) xb2[(size_t)g * kB + b] = make_uint2((unsigned)bal, (unsigned)(bal >> 32));
}

// ---------------------------------------------------------------------------
// FC1 v8: tile M=128,N=64,BK=64; 512 thr = 8 waves (4 waveM x 2 waveN),
// wave tile 32x32, acc[3] (48 AGPR). 4-buffer LDS (4x12KB), stages issued
// 3 phases ahead, counted vmcnt (3/2; never 0 in the loop). B-fragments
// register-prefetched: kk0 set read at END of previous phase (latency
// crosses the barrier), kk1 set read in-phase under the kk0 MFMAs. Post-
// barrier critical path = expand16 -> MFMA. Unroll x4 (buffer period).
// XCD swizzle: panel's 32 M-blocks on one XCD. Grid (32, 98).
// ---------------------------------------------------------------------------
__global__ __launch_bounds__(512, 4) void fc1_v8(
    const uint2* __restrict__ xb2, const signed char* __restrict__ w1lF,
    unsigned* __restrict__ s1b, unsigned* __restrict__ s1T,
    unsigned* __restrict__ cnt, unsigned* __restrict__ list) {
  __shared__ __align__(16) signed char lds[49152];  // 4 x 12 KB
  const int tid = threadIdx.x;
  const int lane = tid & 63;
  const int ln31 = lane & 31;
  const int half = lane >> 5;
  const int wv = tid >> 6;       // 0..7
  const int waveM = wv >> 1;     // 0..3
  const int waveN = wv & 1;      // 0..1

  // XCD-aware swizzle: linear id -> contiguous 392-block chunk per XCD so
  // one panel's 32 M-blocks co-reside on one XCD. 3136 = 8*392 (bijective).
  const int lin = blockIdx.x + 32 * blockIdx.y;     // 0..3135
  const int sw = (lin & 7) * 392 + (lin >> 3);
  const int bx = sw >> 5;        // N-block (64 feats), 0..97
  const int bM = (sw & 31) * 128;

  // B staging: 12 slots/tile; wave wv stages slot wv, and wv+8 if wv<4
  const signed char* const gbase = w1lF + (size_t)bx * 49 * 12288;
  const bool has1 = (wv < 4);
  const unsigned sG0 = wv * 1024u + lane * 16u;
  const unsigned sL0 = wv * 1024u;
  const unsigned sG1 = (wv + 8) * 1024u + lane * 16u;
  const unsigned sL1 = (wv + 8) * 1024u;

  const uint2* const aptr = xb2 + bM + waveM * 32 + ln31;
  const unsigned bfeat = (waveN * 32 + ln31) * 16u;
  const unsigned g0sel = half * 1024u;        // kk=0 fragment group
  const unsigned g1sel = (2 + half) * 1024u;  // kk=1 fragment group

  v16i acc[3] = {};
  v4i bA0, bA1, bA2;  // kk=0 frags of CURRENT tile (prefetched last phase)
  v4i bB0, bB1, bB2;  // kk=1 frags of current tile (read in-phase)
  uint2 aC, aN;

  // WAITM: 0 = steady vmcnt(3)/(2) + barrier; 1 = vmcnt(2) both + barrier;
  //        2 = nothing (last phases).
#define FC1_PHASE(CB, PB, SB, AU, AL, SOFF, AOFF, DO_STAGE, DO_A, DO_PRE, WAITM) \
  {                                                                           \
    bB0 = *(const v4i*)(lds + (CB) + 0 * 4096 + g1sel + bfeat);               \
    bB1 = *(const v4i*)(lds + (CB) + 1 * 4096 + g1sel + bfeat);               \
    bB2 = *(const v4i*)(lds + (CB) + 2 * 4096 + g1sel + bfeat);               \
    if (DO_STAGE) {                                                           \
      gload_lds16(gstage + (SOFF) + sG0, lds + (SB) + sL0);                   \
      if (has1) gload_lds16(gstage + (SOFF) + sG1, lds + (SB) + sL1);         \
    }                                                                         \
    if (DO_A) { (AL) = apre[(size_t)(AOFF)]; }                                \
    {                                                                         \
      const v4i a0 = expand16(((AU).x >> (half * 16)) & 0xFFFFu);             \
      acc[0] = __builtin_amdgcn_mfma_i32_32x32x32_i8(a0, bA0, acc[0], 0,0,0); \
      acc[1] = __builtin_amdgcn_mfma_i32_32x32x32_i8(a0, bA1, acc[1], 0,0,0); \
      acc[2] = __builtin_amdgcn_mfma_i32_32x32x32_i8(a0, bA2, acc[2], 0,0,0); \
      const v4i a1 = expand16(((AU).y >> (half * 16)) & 0xFFFFu);             \
      acc[0] = __builtin_amdgcn_mfma_i32_32x32x32_i8(a1, bB0, acc[0], 0,0,0); \
      acc[1] = __builtin_amdgcn_mfma_i32_32x32x32_i8(a1, bB1, acc[1], 0,0,0); \
      acc[2] = __builtin_amdgcn_mfma_i32_32x32x32_i8(a1, bB2, acc[2], 0,0,0); \
    }                                                                         \
    if (DO_PRE) {                                                             \
      bA0 = *(const v4i*)(lds + (PB) + 0 * 4096 + g0sel + bfeat);             \
      bA1 = *(const v4i*)(lds + (PB) + 1 * 4096 + g0sel + bfeat);             \
      bA2 = *(const v4i*)(lds + (PB) + 2 * 4096 + g0sel + bfeat);             \
    }                                                                         \
    if ((WAITM) == 0) {                                                       \
      if (has1) asm volatile("s_waitcnt vmcnt(3)" ::: "memory");              \
      else      asm volatile("s_waitcnt vmcnt(2)" ::: "memory");              \
      __builtin_amdgcn_s_barrier();                                           \
      asm volatile("" ::: "memory");                                          \
    } else if ((WAITM) == 1) {                                                \
      asm volatile("s_waitcnt vmcnt(2)" ::: "memory");                        \
      __builtin_amdgcn_s_barrier();                                           \
      asm volatile("" ::: "memory");                                          \
    }                                                                         \
  }

  // ---- prologue: stage S(0..2) -> buf0..2; load A(0); certify S0,S1 ----
  gload_lds16(gbase + 0 * 12288 + sG0, lds + 0 + sL0);
  if (has1) gload_lds16(gbase + 0 * 12288 + sG1, lds + 0 + sL1);
  gload_lds16(gbase + 1 * 12288 + sG0, lds + 12288 + sL0);
  if (has1) gload_lds16(gbase + 1 * 12288 + sG1, lds + 12288 + sL1);
  gload_lds16(gbase + 2 * 12288 + sG0, lds + 24576 + sL0);
  if (has1) gload_lds16(gbase + 2 * 12288 + sG1, lds + 24576 + sL1);
  aC = aptr[0];
  asm volatile("s_waitcnt vmcnt(0)" ::: "memory");
  __builtin_amdgcn_s_barrier();
  asm volatile("" ::: "memory");
  // preload tile-0 kk0 fragments into registers
  bA0 = *(const v4i*)(lds + 0 * 4096 + g0sel + bfeat);
  bA1 = *(const v4i*)(lds + 1 * 4096 + g0sel + bfeat);
  bA2 = *(const v4i*)(lds + 2 * 4096 + g0sel + bfeat);

  const uint2* apre = aptr + (size_t)kB;            // -> A(1)
  const signed char* gstage = gbase + 3 * 12288;    // -> S(3)

  // ---- main loop: phases 0..43 (11 x 4; buf period 4, A period 2) ----
  for (int t = 0; t < 11; ++t) {
    FC1_PHASE(0,     12288, 36864, aC, aN, 0,         0,      1, 1, 1, 0);
    FC1_PHASE(12288, 24576, 0,     aN, aC, 12288,     kB,     1, 1, 1, 0);
    FC1_PHASE(24576, 36864, 12288, aC, aN, 2 * 12288, 2 * kB, 1, 1, 1, 0);
    FC1_PHASE(36864, 0,     24576, aN, aC, 3 * 12288, 3 * kB, 1, 1, 1, 0);
    gstage += 4 * 12288;
    apre += (size_t)4 * kB;
  }
  // ---- peeled tail: phases 44..48 ----
  // p=44: stage S47->buf3, load A45
  FC1_PHASE(0,     12288, 36864, aC, aN, 0,     0,      1, 1, 1, 0);
  // p=45: stage S48->buf0, load A46
  FC1_PHASE(12288, 24576, 0,     aN, aC, 12288, kB,     1, 1, 1, 0);
  // p=46: no stage, load A47; wait vmcnt(2) certifies S48
  FC1_PHASE(24576, 36864, 0,     aC, aN, 0,     2 * kB, 0, 1, 1, 1);
  // p=47: no stage, load A48; no wait/barrier needed (no LDS writes follow)
  FC1_PHASE(36864, 0,     0,     aN, aC, 0,     3 * kB, 0, 1, 1, 2);
  // p=48: final compute, nothing to fetch
  FC1_PHASE(0,     0,     0,     aC, aN, 0,     0,      0, 0, 0, 2);
#undef FC1_PHASE

  const double s7 = 0.0078125;
  const int word = bx * 2 + waveN;
  const int fcol = word * 32 + ln31;
#pragma unroll
  for (int t = 0; t < 16; ++t) {
    double v = (double)acc[2][t];
    v = v * s7 + (double)acc[1][t];
    v = v * s7 + (double)acc[0][t];
    v = v * s7;
    const unsigned long long bal = __ballot(v >= 1.0);
    const int mrow = bM + waveM * 32 + (t & 3) + 8 * (t >> 2);
    if (lane == 0) {
      s1b[(size_t)mrow * kFeatWords + word] = (unsigned)bal;
      s1T[(size_t)word * kB + mrow] = (unsigned)bal;
    }
    if (lane == 32) {
      s1b[(size_t)(mrow + 4) * kFeatWords + word] = (unsigned)(bal >> 32);
      s1T[(size_t)word * kB + mrow + 4] = (unsigned)(bal >> 32);
    }
    if (fabs(v - 1.0) <= kTau1) {
      const unsigned idx = atomicAdd(cnt, 1u);
      if (idx < kCap1) list[idx] = ((unsigned)(mrow + 4 * half) << 13) | (unsigned)fcol;
    }
  }
}

// exact fp64 recompute of flagged FC1 dots; fixes s1b AND s1T
__global__ __launch_bounds__(256) void fc1_correct(
    const float* __restrict__ x, const float* __restrict__ W1,
    const unsigned* __restrict__ cnt, const unsigned* __restrict__ list,
    unsigned* __restrict__ s1b, unsigned* __restrict__ s1T) {
  const unsigned n = min(cnt[0], kCap1);
  const int lane = threadIdx.x & 63;
  const int wid = (blockIdx.x * 256 + threadIdx.x) >> 6;
  const int nw = (gridDim.x * 256) >> 6;
  for (unsigned i = wid; i < n; i += nw) {
    const unsigned u = list[i];
    const int b = (int)(u >> 13);
    const int f = (int)(u & 8191u);
    double s = 0.0;
    for (int k = lane; k < kIn; k += 64)
      s = fma((double)x[(size_t)b * kIn + k], (double)W1[(size_t)f * kIn + k], s);
#pragma unroll
    for (int off = 32; off > 0; off >>= 1) s += __shfl_down(s, off);
    if (lane == 0) {
      const unsigned mask = 1u << (f & 31);
      unsigned* p1 = s1b + (size_t)b * kFeatWords + (f >> 5);
      unsigned* p2 = s1T + (size_t)(f >> 5) * kB + b;
      if (s >= 1.0) { atomicOr(p1, mask); atomicOr(p2, mask); }
      else          { atomicAnd(p1, ~mask); atomicAnd(p2, ~mask); }
    }
  }
}

// ---------------------------------------------------------------------------
// FC2 v7: barrier-free register-dbuf, 2-wave blocks (tile 32 rows x 64 outs),
// grid (128, 8) = 1024 blocks -> 8 blocks/CU for latency interleave. A bits
// from s1T, B frags dwordx4 from L2. XCD swizzle: each XCD owns one N-panel.
// ---------------------------------------------------------------------------
__global__ __launch_bounds__(128, 4) void fc2_v7(
    const unsigned* __restrict__ s1T, const signed char* __restrict__ w2lF,
    float* __restrict__ out, unsigned* __restrict__ cnt,
    unsigned* __restrict__ list) {
  const int tid = threadIdx.x;
  const int lane = tid & 63;
  const int ln31 = lane & 31;
  const int half = lane >> 5;
  const int wvN = tid >> 6;    // 0..1 (waveN)

  const int lin = blockIdx.x + 128 * blockIdx.y;    // 0..1023
  const int sw = ((lin & 7) << 7) + (lin >> 3);     // 1024 = 8*128
  const int bx = sw >> 7;      // N-block (64 outs), 0..7
  const int bM = (sw & 127) * 32;

  const unsigned* const aptr = s1T + bM + ln31;
  const int fl = wvN * 32 + ln31;
  const signed char* const bbase =
      w2lF + (size_t)(bx * 98) * 12288 + half * 1024u + fl * 16u;

  v16i acc[3] = {};
  v4i b0[6], b1[6];
  uint2 a0, a1;

#define LOAD_TILE(nk, bf, ab)                                   \
  {                                                             \
    const signed char* bp = bbase + (size_t)(nk) * 12288;       \
    bf[0] = *(const v4i*)(bp);                                  \
    bf[1] = *(const v4i*)(bp + 2048);                           \
    bf[2] = *(const v4i*)(bp + 4096);                           \
    bf[3] = *(const v4i*)(bp + 6144);                           \
    bf[4] = *(const v4i*)(bp + 8192);                           \
    bf[5] = *(const v4i*)(bp + 10240);                          \
    (ab).x = aptr[(size_t)((nk) * 2) * kB];                     \
    (ab).y = aptr[(size_t)((nk) * 2 + 1) * kB];                 \
  }
#define COMPUTE_TILE(bf, ab)                                                    \
  {                                                                             \
    _Pragma("unroll")                                                           \
    for (int kk = 0; kk < 2; ++kk) {                                            \
      const unsigned word = kk ? (ab).y : (ab).x;                               \
      const v4i a = expand16((word >> (half * 16)) & 0xFFFFu);                  \
      acc[0] = __builtin_amdgcn_mfma_i32_32x32x32_i8(a, bf[kk], acc[0], 0,0,0); \
      acc[1] = __builtin_amdgcn_mfma_i32_32x32x32_i8(a, bf[2+kk], acc[1],0,0,0);\
      acc[2] = __builtin_amdgcn_mfma_i32_32x32x32_i8(a, bf[4+kk], acc[2],0,0,0);\
    }                                                                           \
  }

  LOAD_TILE(0, b0, a0);
  for (int kt = 0; kt + 2 <= 98; kt += 2) {
    LOAD_TILE(kt + 1, b1, a1);
    COMPUTE_TILE(b0, a0);
    const int nk2 = (kt + 2 < 98) ? kt + 2 : 97;  // last reload harmless
    LOAD_TILE(nk2, b0, a0);
    COMPUTE_TILE(b1, a1);
  }

  const double s7 = 0.0078125;
  const int o = bx * 64 + wvN * 32 + ln31;
#pragma unroll
  for (int t = 0; t < 16; ++t) {
    double v = (double)acc[2][t];
    v = v * s7 + (double)acc[1][t];
    v = v * s7 + (double)acc[0][t];
    v = v * s7;
    const int b = bM + (t & 3) + 8 * (t >> 2) + 4 * half;
    if (o < kOut) {
      out[(size_t)b * kOut + o] = (v >= 1.0) ? 1.0f : 0.0f;
      if (fabs(v - 1.0) <= kTau2) {
        const unsigned idx = atomicAdd(cnt, 1u);
        if (idx < kCap2) list[idx] = ((unsigned)b << 13) | (unsigned)o;
      }
    }
  }
#undef LOAD_TILE
#undef COMPUTE_TILE
}

// exact fp64 recompute of flagged FC2 dots (reads row-major s1b)
__global__ __launch_bounds__(256) void fc2_correct(
    const unsigned* __restrict__ s1b, const float* __restrict__ W2,
    const unsigned* __restrict__ cnt, const unsigned* __restrict__ list,
    float* __restrict__ out) {
  const unsigned n = min(cnt[0], kCap2);
  const int lane = threadIdx.x & 63;
  const int wid = (blockIdx.x * 256 + threadIdx.x) >> 6;
  const int nw = (gridDim.x * 256) >> 6;
  for (unsigned i = wid; i < n; i += nw) {
    const unsigned u = list[i];
    const int b = (int)(u >> 13);
    const int o = (int)(u & 8191u);
    double s = 0.0;
    for (int k = lane; k < kFeat; k += 64) {
      const unsigned w = s1b[(size_t)b * kFeatWords + (k >> 5)];
      if ((w >> (k & 31)) & 1u) s += (double)W2[(size_t)o * kFeat + k];
    }
#pragma unroll
    for (int off = 32; off > 0; off >>= 1) s += __shfl_down(s, off);
    if (lane == 0) out[(size_t)b * kOut + o] = (s >= 1.0) ? 1.0f : 0.0f;
  }
}

// ---------------------------------------------------------------------------
// fp64 fallback (round-1 validated) — only if ws too small.
// ---------------------------------------------------------------------------
__global__ __launch_bounds__(256) void snn_fc1(const float* __restrict__ x,
                                               const float* __restrict__ W1,
                                               unsigned int* __restrict__ s1bits) {
  __shared__ double Xd[32][66];
  __shared__ double Wd[32][66];
  __shared__ unsigned int spikes[64][2];
  const int tid = threadIdx.x;
  const int tx = tid & 15;
  const int ty = tid >> 4;
  const int b0 = blockIdx.y * 64;
  const int f0 = blockIdx.x * 64;
  if (tid < 128) spikes[tid >> 1][tid & 1] = 0u;
  double acc[4][4];
#pragma unroll
  for (int j = 0; j < 4; ++j)
#pragma unroll
    for (int i = 0; i < 4; ++i) acc[j][i] = 0.0;
  const int rl = tid >> 2;
  const int kq = (tid & 3) * 8;
  const float* xrow = x + (size_t)(b0 + rl) * kIn + kq;
  const float* wrow = W1 + (size_t)(f0 + rl) * kIn + kq;
  for (int kc = 0; kc < kIn; kc += 32) {
    const float4 xv0 = *(const float4*)(xrow + kc);
    const float4 xv1 = *(const float4*)(xrow + kc + 4);
    const float4 wv0 = *(const float4*)(wrow + kc);
    const float4 wv1 = *(const float4*)(wrow + kc + 4);
    __syncthreads();
    Xd[kq + 0][rl] = (double)xv0.x; Xd[kq + 1][rl] = (double)xv0.y;
    Xd[kq + 2][rl] = (double)xv0.z; Xd[kq + 3][rl] = (double)xv0.w;
    Xd[kq + 4][rl] = (double)xv1.x; Xd[kq + 5][rl] = (double)xv1.y;
    Xd[kq + 6][rl] = (double)xv1.z; Xd[kq + 7][rl] = (double)xv1.w;
    Wd[kq + 0][rl] = (double)wv0.x; Wd[kq + 1][rl] = (double)wv0.y;
    Wd[kq + 2][rl] = (double)wv0.z; Wd[kq + 3][rl] = (double)wv0.w;
    Wd[kq + 4][rl] = (double)wv1.x; Wd[kq + 5][rl] = (double)wv1.y;
    Wd[kq + 6][rl] = (double)wv1.z; Wd[kq + 7][rl] = (double)wv1.w;
    __syncthreads();
#pragma unroll
    for (int k = 0; k < 32; ++k) {
      const double2 xa = *(const double2*)&Xd[k][ty * 4];
      const double2 xb = *(const double2*)&Xd[k][ty * 4 + 2];
      const double2 wa = *(const double2*)&Wd[k][tx * 4];
      const double2 wb = *(const double2*)&Wd[k][tx * 4 + 2];
      const double xv[4] = {xa.x, xa.y, xb.x, xb.y};
      const double wv[4] = {wa.x, wa.y, wb.x, wb.y};
#pragma unroll
      for (int j = 0; j < 4; ++j)
#pragma unroll
        for (int i = 0; i < 4; ++i) acc[j][i] += xv[j] * wv[i];
    }
  }
  __syncthreads();
#pragma unroll
  for (int j = 0; j < 4; ++j) {
    unsigned int nib = 0u;
#pragma unroll
    for (int i = 0; i < 4; ++i) nib |= (acc[j][i] >= 1.0 ? 1u : 0u) << i;
    atomicOr(&spikes[ty * 4 + j][tx >> 3], nib << ((tx * 4) & 31));
  }
  __syncthreads();
  if (tid < 128) {
    const int r = tid >> 1;
    const int w = tid & 1;
    s1bits[(size_t)(b0 + r) * kFeatWords + (f0 >> 5) + w] = spikes[r][w];
  }
}

__global__ __launch_bounds__(256) void snn_fc2(const unsigned int* __restrict__ s1bits,
                                               const float* __restrict__ W2,
                                               float* __restrict__ out) {
  __shared__ double Wd[32][66];
  __shared__ unsigned int Sb[64];
  const int tid = threadIdx.x;
  const int tx = tid & 15;
  const int ty = tid >> 4;
  const int b0 = blockIdx.y * 64;
  const int o0 = blockIdx.x * 64;
  double acc[4][4];
#pragma unroll
  for (int j = 0; j < 4; ++j)
#pragma unroll
    for (int i = 0; i < 4; ++i) acc[j][i] = 0.0;
  const int rl = tid >> 2;
  const int kq = (tid & 3) * 8;
  int orow = o0 + rl;
  if (orow >= kOut) orow = kOut - 1;
  const float* wrow = W2 + (size_t)orow * kFeat + kq;
  for (int kc = 0; kc < kFeat; kc += 32) {
    const float4 wv0 = *(const float4*)(wrow + kc);
    const float4 wv1 = *(const float4*)(wrow + kc + 4);
    unsigned int sword = 0u;
    if (tid < 64) sword = s1bits[(size_t)(b0 + tid) * kFeatWords + (kc >> 5)];
    __syncthreads();
    Wd[kq + 0][rl] = (double)wv0.x; Wd[kq + 1][rl] = (double)wv0.y;
    Wd[kq + 2][rl] = (double)wv0.z; Wd[kq + 3][rl] = (double)wv0.w;
    Wd[kq + 4][rl] = (double)wv1.x; Wd[kq + 5][rl] = (double)wv1.y;
    Wd[kq + 6][rl] = (double)wv1.z; Wd[kq + 7][rl] = (double)wv1.w;
    if (tid < 64) Sb[tid] = sword;
    __syncthreads();
    const unsigned int rw0 = Sb[ty * 4 + 0];
    const unsigned int rw1 = Sb[ty * 4 + 1];
    const unsigned int rw2 = Sb[ty * 4 + 2];
    const unsigned int rw3 = Sb[ty * 4 + 3];
#pragma unroll
    for (int k = 0; k < 32; ++k) {
      const double2 wa = *(const double2*)&Wd[k][tx * 4];
      const double2 wb = *(const double2*)&Wd[k][tx * 4 + 2];
      const double wv[4] = {wa.x, wa.y, wb.x, wb.y};
      const double sv[4] = {(double)((rw0 >> k) & 1u), (double)((rw1 >> k) & 1u),
                            (double)((rw2 >> k) & 1u), (double)((rw3 >> k) & 1u)};
#pragma unroll
      for (int j = 0; j < 4; ++j)
#pragma unroll
        for (int i = 0; i < 4; ++i) acc[j][i] += sv[j] * wv[i];
    }
  }
#pragma unroll
  for (int j = 0; j < 4; ++j) {
    const int b = b0 + ty * 4 + j;
#pragma unroll
    for (int i = 0; i < 4; ++i) {
      const int o = o0 + tx * 4 + i;
      if (o < kOut) out[(size_t)b * kOut + o] = (acc[j][i] >= 1.0) ? 1.0f : 0.0f;
    }
  }
}

extern "C" void kernel_launch(void* const* d_in, const int* in_sizes, int n_in,
                              void* d_out, int out_size, void* d_ws, size_t ws_size,
                              hipStream_t stream) {
  const float* x = (const float*)d_in[0];
  const float* W1 = (const float*)d_in[1];
  const float* W2 = (const float*)d_in[2];
  float* out = (float*)d_out;

  char* p = (char*)d_ws;
  signed char* w1lF = (signed char*)p;   p += kW1F;
  signed char* w2lF = (signed char*)p;   p += kW2F;
  unsigned* s1b = (unsigned*)p;          p += kS1Bytes;
  unsigned* s1T = (unsigned*)p;          p += kS1Bytes;
  uint2* xb2 = (uint2*)p;                p += kXb2Bytes;
  unsigned* list1 = (unsigned*)p;        p += (size_t)kCap1 * 4;
  unsigned* list2 = (unsigned*)p;        p += (size_t)kCap2 * 4;
  unsigned* ctrs = (unsigned*)p;         p += 256;
  const size_t need = (size_t)(p - (char*)d_ws);  // ~85 MB

  if (ws_size >= need) {
    hipMemsetAsync(ctrs, 0, 32, stream);  // ctrs[0]=fc1 cnt, ctrs[4]=fc2 cnt
    conv_w1F<<<4802, 256, 0, stream>>>(W1, w1lF);
    conv_w2F<<<784, 256, 0, stream>>>(W2, w2lF);
    pack_x2<<<50176, 256, 0, stream>>>(x, xb2);
    fc1_v8<<<dim3(32, 98), 512, 0, stream>>>(xb2, w1lF, s1b, s1T, ctrs, list1);
    fc1_correct<<<1024, 256, 0, stream>>>(x, W1, ctrs, list1, s1b, s1T);
    fc2_v7<<<dim3(128, 8), 128, 0, stream>>>(s1T, w2lF, out, ctrs + 4, list2);
    fc2_correct<<<64, 256, 0, stream>>>(s1b, W2, ctrs + 4, list2, out);
  } else {
    unsigned* s1 = (unsigned*)d_ws;
    snn_fc1<<<dim3(98, 64), 256, 0, stream>>>(x, W1, s1);
    snn_fc2<<<dim3(8, 64), 256, 0, stream>>>(s1, W2, out);
  }
}

// Round 4
// 574.108 us; speedup vs baseline: 1.0242x; 1.0225x over previous
//
#include <hip/hip_runtime.h>

// SNN 2-layer forward: s2 = (( (x@W1.T >=1) @ W2.T) >= 1)
// B=4096, IN=3136, FEAT=6272, OUT=500; x and s1 binary {0,1}.
// Exact 3-limb i8-MFMA GEMM (w = d0*2^-7+d1*2^-14+d2*2^-21+r, |r|<=2^-22,
// i32 MFMA accumulation exact, f64 Horner exact) + worst-case-safe sparse
// fp64 correction of all dots with |v_hat-1| <= K*2^-22.
//
// Round-12: scheduling attempts v7 (counted vmcnt) and v8 (reg prefetch)
// were both SLOWER than v6's plain __syncthreads drain (256 -> 279 -> 296
// us) -> the ~1200cy/phase overhead (barrier+drain+front latency+skew) is
// FIXED per phase, not removable by source-level scheduling (matches
// m99/m131-m141). Lever: amortize it. fc1_v9 = v6 structure with BK=192
// (3 kt per phase): 17 barriers instead of 49, 2x36KB LDS dbuf (72KB/block
// -> still 2 blocks/CU, 144<160KB), 18 MFMA/wave/phase. Per-phase =
// 3*878 MFMA + ~1170 OH -> predicted fc1 ~165us, MfmaUtil ~60%.
// XCD swizzle kept (FETCH 236->40MB). No asm waitcnt, no setprio.

namespace {
constexpr int kB = 4096;
constexpr int kIn = 3136;        // 49 chunks of 64
constexpr int kFeat = 6272;      // 98 chunks of 64
constexpr int kFeatWords = 196;  // u32 per s1 row
constexpr int kOut = 500;
constexpr size_t kPlane1 = (size_t)kFeat * kIn;
constexpr size_t kW1F = 3 * kPlane1;                 // 59,006,976 (4802*12288)
constexpr size_t kW2F = (size_t)784 * 12288;         // 9,633,792
constexpr size_t kS1Bytes = (size_t)kB * kFeatWords * 4;  // 3,211,264 (x2)
constexpr size_t kXb2Bytes = (size_t)49 * kB * 8;    // 1,605,632
constexpr unsigned kCap1 = 2u << 20;
constexpr unsigned kCap2 = 1u << 16;
__device__ constexpr double kTau1 = 7.4769e-4;       // > 3136*2^-22
__device__ constexpr double kTau2 = 1.4955e-3;       // > 6272*2^-22
}  // namespace

typedef int v4i __attribute__((ext_vector_type(4)));
typedef int v16i __attribute__((ext_vector_type(16)));

__device__ __forceinline__ void gload_lds16(const void* g, void* l) {
  __builtin_amdgcn_global_load_lds((__attribute__((address_space(1))) void*)(g),
                                   (__attribute__((address_space(3))) void*)(l),
                                   16, 0, 0);
}

// 16 bits -> 16 i8 (byte i = bit i)
__device__ __forceinline__ v4i expand16(unsigned b) {
  unsigned u0 = (((b      ) & 0xFu) * 0x204081u) & 0x01010101u;
  unsigned u1 = (((b >> 4 ) & 0xFu) * 0x204081u) & 0x01010101u;
  unsigned u2 = (((b >> 8 ) & 0xFu) * 0x204081u) & 0x01010101u;
  unsigned u3 = (((b >> 12) & 0xFu) * 0x204081u) & 0x01010101u;
  return (v4i){(int)u0, (int)u1, (int)u2, (int)u3};
}

// exact 3-digit signed base-128 split; |w - sum| <= 2^-22
__device__ __forceinline__ void split3(float w, signed char* d) {
  float c = rintf(w * 128.f);
  d[0] = (signed char)(int)c;
  float r = fmaf(c, -7.8125e-03f, w);
  c = rintf(r * 16384.f);
  d[1] = (signed char)(int)c;
  r = fmaf(c, -6.103515625e-05f, r);
  c = rintf(r * 2097152.f);
  d[2] = (signed char)(int)c;
}

// ---------------------------------------------------------------------------
// W1 -> fragment-major limbs: slot(fb,kt,j,g) = 1KB of 64 feats x 16 k-bytes.
// ---------------------------------------------------------------------------
__global__ __launch_bounds__(256) void conv_w1F(const float* __restrict__ W,
                                                signed char* __restrict__ F) {
  const int bx = blockIdx.x;               // fb*49 + kt, < 4802
  const int fb = bx / 49;
  const int kt = bx % 49;
  const int f = threadIdx.x & 63;
  const int g = threadIdx.x >> 6;
  const float* src = W + (size_t)(fb * 64 + f) * kIn + kt * 64 + g * 16;
  union { signed char c[16]; int4 v; } o[3];
#pragma unroll
  for (int q = 0; q < 4; ++q) {
    const float4 w = *(const float4*)(src + q * 4);
    signed char d[4][3];
    split3(w.x, d[0]); split3(w.y, d[1]); split3(w.z, d[2]); split3(w.w, d[3]);
#pragma unroll
    for (int e = 0; e < 4; ++e)
#pragma unroll
      for (int j = 0; j < 3; ++j) o[j].c[q * 4 + e] = d[e][j];
  }
#pragma unroll
  for (int j = 0; j < 3; ++j)
    *(int4*)(F + ((size_t)bx * 3 + j) * 4096 + g * 1024 + f * 16) = o[j].v;
}

// W2 (padded to 512 rows) -> fragment-major limbs, slots (fb<8, kt<98, j, g)
__global__ __launch_bounds__(256) void conv_w2F(const float* __restrict__ W,
                                                signed char* __restrict__ F) {
  const int bx = blockIdx.x;               // fb*98 + kt, < 784
  const int fb = bx / 98;
  const int kt = bx % 98;
  const int f = threadIdx.x & 63;
  const int g = threadIdx.x >> 6;
  const int feat = fb * 64 + f;
  union { signed char c[16]; int4 v; } o[3];
#pragma unroll
  for (int q = 0; q < 4; ++q) {
    float4 w = {0.f, 0.f, 0.f, 0.f};
    if (feat < kOut)
      w = *(const float4*)(W + (size_t)feat * kFeat + kt * 64 + g * 16 + q * 4);
    signed char d[4][3];
    split3(w.x, d[0]); split3(w.y, d[1]); split3(w.z, d[2]); split3(w.w, d[3]);
#pragma unroll
    for (int e = 0; e < 4; ++e)
#pragma unroll
      for (int j = 0; j < 3; ++j) o[j].c[q * 4 + e] = d[e][j];
  }
#pragma unroll
  for (int j = 0; j < 3; ++j)
    *(int4*)(F + ((size_t)bx * 3 + j) * 4096 + g * 1024 + f * 16) = o[j].v;
}

// x -> transposed packed bits: xb2[kt*4096 + b]
__global__ __launch_bounds__(256) void pack_x2(const float* __restrict__ X,
                                               uint2* __restrict__ xb2) {
  const int wid = (blockIdx.x * 256 + threadIdx.x) >> 6;  // < 200,704
  const int lane = threadIdx.x & 63;
  const int b = wid / 49;
  const int g = wid % 49;
  const float v = X[(size_t)b * kIn + g * 64 + lane];
  const unsigned long long bal = __ballot(v != 0.f);
  if (lane == 0) xb2[(size_t)g * kB + b] = make_uint2((unsigned)bal, (unsigned)(bal >> 32));
}

// ---------------------------------------------------------------------------
// FC1 v9: tile M=128,N=64,BK=192 (3 kt/phase); 512 thr = 8 waves
// (4 waveM x 2 waveN), wave tile 32x32, acc[3] (48 AGPR). v6's simple
// __syncthreads-drain double-buffer, but 2x36KB buffers -> 17 barriers
// instead of 49; per-phase fixed overhead amortized over 18 MFMA/wave.
// Staging: 36 slots/phase; wave wv stages slots wv,wv+8,wv+16,wv+24
// (+wv+32 if wv<4). Tail: phase 16 computes kt=48 only (12KB half-stage).
// XCD swizzle: panel's 32 M-blocks on one XCD. Grid (32, 98).
// ---------------------------------------------------------------------------
__global__ __launch_bounds__(512, 4) void fc1_v9(
    const uint2* __restrict__ xb2, const signed char* __restrict__ w1lF,
    unsigned* __restrict__ s1b, unsigned* __restrict__ s1T,
    unsigned* __restrict__ cnt, unsigned* __restrict__ list) {
  __shared__ __align__(16) signed char lds[73728];  // 2 x 36 KB
  const int tid = threadIdx.x;
  const int lane = tid & 63;
  const int ln31 = lane & 31;
  const int half = lane >> 5;
  const int wv = tid >> 6;       // 0..7
  const int waveM = wv >> 1;     // 0..3
  const int waveN = wv & 1;      // 0..1

  // XCD-aware swizzle: linear id -> contiguous 392-block chunk per XCD so
  // one panel's 32 M-blocks co-reside on one XCD. 3136 = 8*392 (bijective).
  const int lin = blockIdx.x + 32 * blockIdx.y;     // 0..3135
  const int sw = (lin & 7) * 392 + (lin >> 3);
  const int bx = sw >> 5;        // N-block (64 feats), 0..97
  const int bM = (sw & 31) * 128;

  const signed char* const gbase = w1lF + (size_t)bx * 49 * 12288;
  const unsigned sG0 = wv * 1024u + lane * 16u;  // global: slot base + lane
  const unsigned sL0 = wv * 1024u;               // lds: slot base

  const uint2* const aptr = xb2 + bM + waveM * 32 + ln31;
  const unsigned bfeat = (waveN * 32 + ln31) * 16u;
  const unsigned gs0 = half * 1024u;    // kk=0 fragment group
  const unsigned gs1 = gs0 + 2048u;     // kk=1 fragment group

  v16i acc[3] = {};
  uint2 aC0, aC1, aC2, aN0, aN1, aN2;

  // one kt-tile: 2 kk halves x 3 limb MFMAs
#define FC1_KT(TB, AW)                                                        \
  {                                                                           \
    const v4i b0 = *(const v4i*)(lds + (TB) + 0 * 4096 + gs0 + bfeat);        \
    const v4i b1 = *(const v4i*)(lds + (TB) + 1 * 4096 + gs0 + bfeat);        \
    const v4i b2 = *(const v4i*)(lds + (TB) + 2 * 4096 + gs0 + bfeat);        \
    const v4i a0 = expand16(((AW).x >> (half * 16)) & 0xFFFFu);               \
    acc[0] = __builtin_amdgcn_mfma_i32_32x32x32_i8(a0, b0, acc[0], 0, 0, 0);  \
    acc[1] = __builtin_amdgcn_mfma_i32_32x32x32_i8(a0, b1, acc[1], 0, 0, 0);  \
    acc[2] = __builtin_amdgcn_mfma_i32_32x32x32_i8(a0, b2, acc[2], 0, 0, 0);  \
    const v4i c0 = *(const v4i*)(lds + (TB) + 0 * 4096 + gs1 + bfeat);        \
    const v4i c1 = *(const v4i*)(lds + (TB) + 1 * 4096 + gs1 + bfeat);        \
    const v4i c2 = *(const v4i*)(lds + (TB) + 2 * 4096 + gs1 + bfeat);        \
    const v4i a1 = expand16(((AW).y >> (half * 16)) & 0xFFFFu);               \
    acc[0] = __builtin_amdgcn_mfma_i32_32x32x32_i8(a1, c0, acc[0], 0, 0, 0);  \
    acc[1] = __builtin_amdgcn_mfma_i32_32x32x32_i8(a1, c1, acc[1], 0, 0, 0);  \
    acc[2] = __builtin_amdgcn_mfma_i32_32x32x32_i8(a1, c2, acc[2], 0, 0, 0);  \
  }

  // ---- prologue: stage phase 0 (kt 0..2 -> buf0, 36 slots); A(0..2) ----
  gload_lds16(gbase + sG0, lds + sL0);
  gload_lds16(gbase + 8192 + sG0, lds + 8192 + sL0);
  gload_lds16(gbase + 16384 + sG0, lds + 16384 + sL0);
  gload_lds16(gbase + 24576 + sG0, lds + 24576 + sL0);
  if (wv < 4) gload_lds16(gbase + 32768 + sG0, lds + 32768 + sL0);
  aC0 = aptr[0];
  aC1 = aptr[(size_t)kB];
  aC2 = aptr[(size_t)2 * kB];

  // ---- 17 phases: p<16 full (kt 3p..3p+2), p==16 single (kt 48) ----
  for (int p = 0; p < 17; ++p) {
    __syncthreads();  // drains stage(p) + A-prefetches; prev compute done
    const int cb = (p & 1) * 36864;
    if (p < 16) {
      const int nb = ((p + 1) & 1) * 36864;
      const size_t go = (size_t)(p + 1) * 36864;
      if (p < 15) {  // full 36KB stage of kt 3p+3..3p+5
        gload_lds16(gbase + go + sG0, lds + nb + sL0);
        gload_lds16(gbase + go + 8192 + sG0, lds + nb + 8192 + sL0);
        gload_lds16(gbase + go + 16384 + sG0, lds + nb + 16384 + sL0);
        gload_lds16(gbase + go + 24576 + sG0, lds + nb + 24576 + sL0);
        if (wv < 4) gload_lds16(gbase + go + 32768 + sG0, lds + nb + 32768 + sL0);
      } else {       // p==15: stage kt=48 only (12KB)
        gload_lds16(gbase + go + sG0, lds + nb + sL0);
        if (wv < 4) gload_lds16(gbase + go + 8192 + sG0, lds + nb + 8192 + sL0);
      }
      const int k1 = 3 * p + 4 < 49 ? 3 * p + 4 : 48;
      const int k2 = 3 * p + 5 < 49 ? 3 * p + 5 : 48;
      aN0 = aptr[(size_t)(3 * p + 3) * kB];
      aN1 = aptr[(size_t)k1 * kB];
      aN2 = aptr[(size_t)k2 * kB];
    }
    FC1_KT(cb, aC0);
    if (p < 16) {
      FC1_KT(cb + 12288, aC1);
      FC1_KT(cb + 24576, aC2);
    }
    aC0 = aN0;
    aC1 = aN1;
    aC2 = aN2;
  }
#undef FC1_KT

  const double s7 = 0.0078125;
  const int word = bx * 2 + waveN;
  const int fcol = word * 32 + ln31;
#pragma unroll
  for (int t = 0; t < 16; ++t) {
    double v = (double)acc[2][t];
    v = v * s7 + (double)acc[1][t];
    v = v * s7 + (double)acc[0][t];
    v = v * s7;
    const unsigned long long bal = __ballot(v >= 1.0);
    const int mrow = bM + waveM * 32 + (t & 3) + 8 * (t >> 2);
    if (lane == 0) {
      s1b[(size_t)mrow * kFeatWords + word] = (unsigned)bal;
      s1T[(size_t)word * kB + mrow] = (unsigned)bal;
    }
    if (lane == 32) {
      s1b[(size_t)(mrow + 4) * kFeatWords + word] = (unsigned)(bal >> 32);
      s1T[(size_t)word * kB + mrow + 4] = (unsigned)(bal >> 32);
    }
    if (fabs(v - 1.0) <= kTau1) {
      const unsigned idx = atomicAdd(cnt, 1u);
      if (idx < kCap1) list[idx] = ((unsigned)(mrow + 4 * half) << 13) | (unsigned)fcol;
    }
  }
}

// exact fp64 recompute of flagged FC1 dots; fixes s1b AND s1T
__global__ __launch_bounds__(256) void fc1_correct(
    const float* __restrict__ x, const float* __restrict__ W1,
    const unsigned* __restrict__ cnt, const unsigned* __restrict__ list,
    unsigned* __restrict__ s1b, unsigned* __restrict__ s1T) {
  const unsigned n = min(cnt[0], kCap1);
  const int lane = threadIdx.x & 63;
  const int wid = (blockIdx.x * 256 + threadIdx.x) >> 6;
  const int nw = (gridDim.x * 256) >> 6;
  for (unsigned i = wid; i < n; i += nw) {
    const unsigned u = list[i];
    const int b = (int)(u >> 13);
    const int f = (int)(u & 8191u);
    double s = 0.0;
    for (int k = lane; k < kIn; k += 64)
      s = fma((double)x[(size_t)b * kIn + k], (double)W1[(size_t)f * kIn + k], s);
#pragma unroll
    for (int off = 32; off > 0; off >>= 1) s += __shfl_down(s, off);
    if (lane == 0) {
      const unsigned mask = 1u << (f & 31);
      unsigned* p1 = s1b + (size_t)b * kFeatWords + (f >> 5);
      unsigned* p2 = s1T + (size_t)(f >> 5) * kB + b;
      if (s >= 1.0) { atomicOr(p1, mask); atomicOr(p2, mask); }
      else          { atomicAnd(p1, ~mask); atomicAnd(p2, ~mask); }
    }
  }
}

// ---------------------------------------------------------------------------
// FC2 v7: barrier-free register-dbuf, 2-wave blocks (tile 32 rows x 64 outs),
// grid (128, 8) = 1024 blocks -> 8 blocks/CU for latency interleave. A bits
// from s1T, B frags dwordx4 from L2. XCD swizzle: each XCD owns one N-panel.
// ---------------------------------------------------------------------------
__global__ __launch_bounds__(128, 4) void fc2_v7(
    const unsigned* __restrict__ s1T, const signed char* __restrict__ w2lF,
    float* __restrict__ out, unsigned* __restrict__ cnt,
    unsigned* __restrict__ list) {
  const int tid = threadIdx.x;
  const int lane = tid & 63;
  const int ln31 = lane & 31;
  const int half = lane >> 5;
  const int wvN = tid >> 6;    // 0..1 (waveN)

  const int lin = blockIdx.x + 128 * blockIdx.y;    // 0..1023
  const int sw = ((lin & 7) << 7) + (lin >> 3);     // 1024 = 8*128
  const int bx = sw >> 7;      // N-block (64 outs), 0..7
  const int bM = (sw & 127) * 32;

  const unsigned* const aptr = s1T + bM + ln31;
  const int fl = wvN * 32 + ln31;
  const signed char* const bbase =
      w2lF + (size_t)(bx * 98) * 12288 + half * 1024u + fl * 16u;

  v16i acc[3] = {};
  v4i b0[6], b1[6];
  uint2 a0, a1;

#define LOAD_TILE(nk, bf, ab)                                   \
  {                                                             \
    const signed char* bp = bbase + (size_t)(nk) * 12288;       \
    bf[0] = *(const v4i*)(bp);                                  \
    bf[1] = *(const v4i*)(bp + 2048);                           \
    bf[2] = *(const v4i*)(bp + 4096);                           \
    bf[3] = *(const v4i*)(bp + 6144);                           \
    bf[4] = *(const v4i*)(bp + 8192);                           \
    bf[5] = *(const v4i*)(bp + 10240);                          \
    (ab).x = aptr[(size_t)((nk) * 2) * kB];                     \
    (ab).y = aptr[(size_t)((nk) * 2 + 1) * kB];                 \
  }
#define COMPUTE_TILE(bf, ab)                                                    \
  {                                                                             \
    _Pragma("unroll")                                                           \
    for (int kk = 0; kk < 2; ++kk) {                                            \
      const unsigned word = kk ? (ab).y : (ab).x;                               \
      const v4i a = expand16((word >> (half * 16)) & 0xFFFFu);                  \
      acc[0] = __builtin_amdgcn_mfma_i32_32x32x32_i8(a, bf[kk], acc[0], 0,0,0); \
      acc[1] = __builtin_amdgcn_mfma_i32_32x32x32_i8(a, bf[2+kk], acc[1],0,0,0);\
      acc[2] = __builtin_amdgcn_mfma_i32_32x32x32_i8(a, bf[4+kk], acc[2],0,0,0);\
    }                                                                           \
  }

  LOAD_TILE(0, b0, a0);
  for (int kt = 0; kt + 2 <= 98; kt += 2) {
    LOAD_TILE(kt + 1, b1, a1);
    COMPUTE_TILE(b0, a0);
    const int nk2 = (kt + 2 < 98) ? kt + 2 : 97;  // last reload harmless
    LOAD_TILE(nk2, b0, a0);
    COMPUTE_TILE(b1, a1);
  }

  const double s7 = 0.0078125;
  const int o = bx * 64 + wvN * 32 + ln31;
#pragma unroll
  for (int t = 0; t < 16; ++t) {
    double v = (double)acc[2][t];
    v = v * s7 + (double)acc[1][t];
    v = v * s7 + (double)acc[0][t];
    v = v * s7;
    const int b = bM + (t & 3) + 8 * (t >> 2) + 4 * half;
    if (o < kOut) {
      out[(size_t)b * kOut + o] = (v >= 1.0) ? 1.0f : 0.0f;
      if (fabs(v - 1.0) <= kTau2) {
        const unsigned idx = atomicAdd(cnt, 1u);
        if (idx < kCap2) list[idx] = ((unsigned)b << 13) | (unsigned)o;
      }
    }
  }
#undef LOAD_TILE
#undef COMPUTE_TILE
}

// exact fp64 recompute of flagged FC2 dots (reads row-major s1b)
__global__ __launch_bounds__(256) void fc2_correct(
    const unsigned* __restrict__ s1b, const float* __restrict__ W2,
    const unsigned* __restrict__ cnt, const unsigned* __restrict__ list,
    float* __restrict__ out) {
  const unsigned n = min(cnt[0], kCap2);
  const int lane = threadIdx.x & 63;
  const int wid = (blockIdx.x * 256 + threadIdx.x) >> 6;
  const int nw = (gridDim.x * 256) >> 6;
  for (unsigned i = wid; i < n; i += nw) {
    const unsigned u = list[i];
    const int b = (int)(u >> 13);
    const int o = (int)(u & 8191u);
    double s = 0.0;
    for (int k = lane; k < kFeat; k += 64) {
      const unsigned w = s1b[(size_t)b * kFeatWords + (k >> 5)];
      if ((w >> (k & 31)) & 1u) s += (double)W2[(size_t)o * kFeat + k];
    }
#pragma unroll
    for (int off = 32; off > 0; off >>= 1) s += __shfl_down(s, off);
    if (lane == 0) out[(size_t)b * kOut + o] = (s >= 1.0) ? 1.0f : 0.0f;
  }
}

// ---------------------------------------------------------------------------
// fp64 fallback (round-1 validated) — only if ws too small.
// ---------------------------------------------------------------------------
__global__ __launch_bounds__(256) void snn_fc1(const float* __restrict__ x,
                                               const float* __restrict__ W1,
                                               unsigned int* __restrict__ s1bits) {
  __shared__ double Xd[32][66];
  __shared__ double Wd[32][66];
  __shared__ unsigned int spikes[64][2];
  const int tid = threadIdx.x;
  const int tx = tid & 15;
  const int ty = tid >> 4;
  const int b0 = blockIdx.y * 64;
  const int f0 = blockIdx.x * 64;
  if (tid < 128) spikes[tid >> 1][tid & 1] = 0u;
  double acc[4][4];
#pragma unroll
  for (int j = 0; j < 4; ++j)
#pragma unroll
    for (int i = 0; i < 4; ++i) acc[j][i] = 0.0;
  const int rl = tid >> 2;
  const int kq = (tid & 3) * 8;
  const float* xrow = x + (size_t)(b0 + rl) * kIn + kq;
  const float* wrow = W1 + (size_t)(f0 + rl) * kIn + kq;
  for (int kc = 0; kc < kIn; kc += 32) {
    const float4 xv0 = *(const float4*)(xrow + kc);
    const float4 xv1 = *(const float4*)(xrow + kc + 4);
    const float4 wv0 = *(const float4*)(wrow + kc);
    const float4 wv1 = *(const float4*)(wrow + kc + 4);
    __syncthreads();
    Xd[kq + 0][rl] = (double)xv0.x; Xd[kq + 1][rl] = (double)xv0.y;
    Xd[kq + 2][rl] = (double)xv0.z; Xd[kq + 3][rl] = (double)xv0.w;
    Xd[kq + 4][rl] = (double)xv1.x; Xd[kq + 5][rl] = (double)xv1.y;
    Xd[kq + 6][rl] = (double)xv1.z; Xd[kq + 7][rl] = (double)xv1.w;
    Wd[kq + 0][rl] = (double)wv0.x; Wd[kq + 1][rl] = (double)wv0.y;
    Wd[kq + 2][rl] = (double)wv0.z; Wd[kq + 3][rl] = (double)wv0.w;
    Wd[kq + 4][rl] = (double)wv1.x; Wd[kq + 5][rl] = (double)wv1.y;
    Wd[kq + 6][rl] = (double)wv1.z; Wd[kq + 7][rl] = (double)wv1.w;
    __syncthreads();
#pragma unroll
    for (int k = 0; k < 32; ++k) {
      const double2 xa = *(const double2*)&Xd[k][ty * 4];
      const double2 xb = *(const double2*)&Xd[k][ty * 4 + 2];
      const double2 wa = *(const double2*)&Wd[k][tx * 4];
      const double2 wb = *(const double2*)&Wd[k][tx * 4 + 2];
      const double xv[4] = {xa.x, xa.y, xb.x, xb.y};
      const double wv[4] = {wa.x, wa.y, wb.x, wb.y};
#pragma unroll
      for (int j = 0; j < 4; ++j)
#pragma unroll
        for (int i = 0; i < 4; ++i) acc[j][i] += xv[j] * wv[i];
    }
  }
  __syncthreads();
#pragma unroll
  for (int j = 0; j < 4; ++j) {
    unsigned int nib = 0u;
#pragma unroll
    for (int i = 0; i < 4; ++i) nib |= (acc[j][i] >= 1.0 ? 1u : 0u) << i;
    atomicOr(&spikes[ty * 4 + j][tx >> 3], nib << ((tx * 4) & 31));
  }
  __syncthreads();
  if (tid < 128) {
    const int r = tid >> 1;
    const int w = tid & 1;
    s1bits[(size_t)(b0 + r) * kFeatWords + (f0 >> 5) + w] = spikes[r][w];
  }
}

__global__ __launch_bounds__(256) void snn_fc2(const unsigned int* __restrict__ s1bits,
                                               const float* __restrict__ W2,
                                               float* __restrict__ out) {
  __shared__ double Wd[32][66];
  __shared__ unsigned int Sb[64];
  const int tid = threadIdx.x;
  const int tx = tid & 15;
  const int ty = tid >> 4;
  const int b0 = blockIdx.y * 64;
  const int o0 = blockIdx.x * 64;
  double acc[4][4];
#pragma unroll
  for (int j = 0; j < 4; ++j)
#pragma unroll
    for (int i = 0; i < 4; ++i) acc[j][i] = 0.0;
  const int rl = tid >> 2;
  const int kq = (tid & 3) * 8;
  int orow = o0 + rl;
  if (orow >= kOut) orow = kOut - 1;
  const float* wrow = W2 + (size_t)orow * kFeat + kq;
  for (int kc = 0; kc < kFeat; kc += 32) {
    const float4 wv0 = *(const float4*)(wrow + kc);
    const float4 wv1 = *(const float4*)(wrow + kc + 4);
    unsigned int sword = 0u;
    if (tid < 64) sword = s1bits[(size_t)(b0 + tid) * kFeatWords + (kc >> 5)];
    __syncthreads();
    Wd[kq + 0][rl] = (double)wv0.x; Wd[kq + 1][rl] = (double)wv0.y;
    Wd[kq + 2][rl] = (double)wv0.z; Wd[kq + 3][rl] = (double)wv0.w;
    Wd[kq + 4][rl] = (double)wv1.x; Wd[kq + 5][rl] = (double)wv1.y;
    Wd[kq + 6][rl] = (double)wv1.z; Wd[kq + 7][rl] = (double)wv1.w;
    if (tid < 64) Sb[tid] = sword;
    __syncthreads();
    const unsigned int rw0 = Sb[ty * 4 + 0];
    const unsigned int rw1 = Sb[ty * 4 + 1];
    const unsigned int rw2 = Sb[ty * 4 + 2];
    const unsigned int rw3 = Sb[ty * 4 + 3];
#pragma unroll
    for (int k = 0; k < 32; ++k) {
      const double2 wa = *(const double2*)&Wd[k][tx * 4];
      const double2 wb = *(const double2*)&Wd[k][tx * 4 + 2];
      const double wv[4] = {wa.x, wa.y, wb.x, wb.y};
      const double sv[4] = {(double)((rw0 >> k) & 1u), (double)((rw1 >> k) & 1u),
                            (double)((rw2 >> k) & 1u), (double)((rw3 >> k) & 1u)};
#pragma unroll
      for (int j = 0; j < 4; ++j)
#pragma unroll
        for (int i = 0; i < 4; ++i) acc[j][i] += sv[j] * wv[i];
    }
  }
#pragma unroll
  for (int j = 0; j < 4; ++j) {
    const int b = b0 + ty * 4 + j;
#pragma unroll
    for (int i = 0; i < 4; ++i) {
      const int o = o0 + tx * 4 + i;
      if (o < kOut) out[(size_t)b * kOut + o] = (acc[j][i] >= 1.0) ? 1.0f : 0.0f;
    }
  }
}

extern "C" void kernel_launch(void* const* d_in, const int* in_sizes, int n_in,
                              void* d_out, int out_size, void* d_ws, size_t ws_size,
                              hipStream_t stream) {
  const float* x = (const float*)d_in[0];
  const float* W1 = (const float*)d_in[1];
  const float* W2 = (const float*)d_in[2];
  float* out = (float*)d_out;

  char* p = (char*)d_ws;
  signed char* w1lF = (signed char*)p;   p += kW1F;
  signed char* w2lF = (signed char*)p;   p += kW2F;
  unsigned* s1b = (unsigned*)p;          p += kS1Bytes;
  unsigned* s1T = (unsigned*)p;          p += kS1Bytes;
  uint2* xb2 = (uint2*)p;                p += kXb2Bytes;
  unsigned* list1 = (unsigned*)p;        p += (size_t)kCap1 * 4;
  unsigned* list2 = (unsigned*)p;        p += (size_t)kCap2 * 4;
  unsigned* ctrs = (unsigned*)p;         p += 256;
  const size_t need = (size_t)(p - (char*)d_ws);  // ~85 MB

  if (ws_size >= need) {
    hipMemsetAsync(ctrs, 0, 32, stream);  // ctrs[0]=fc1 cnt, ctrs[4]=fc2 cnt
    conv_w1F<<<4802, 256, 0, stream>>>(W1, w1lF);
    conv_w2F<<<784, 256, 0, stream>>>(W2, w2lF);
    pack_x2<<<50176, 256, 0, stream>>>(x, xb2);
    fc1_v9<<<dim3(32, 98), 512, 0, stream>>>(xb2, w1lF, s1b, s1T, ctrs, list1);
    fc1_correct<<<1024, 256, 0, stream>>>(x, W1, ctrs, list1, s1b, s1T);
    fc2_v7<<<dim3(128, 8), 128, 0, stream>>>(s1T, w2lF, out, ctrs + 4, list2);
    fc2_correct<<<64, 256, 0, stream>>>(s1b, W2, ctrs + 4, list2, out);
  } else {
    unsigned* s1 = (unsigned*)d_ws;
    snn_fc1<<<dim3(98, 64), 256, 0, stream>>>(x, W1, s1);
    snn_fc2<<<dim3(8, 64), 256, 0, stream>>>(s1, W2, out);
  }
}